// Round 6
// baseline (276.637 us; speedup 1.0000x reference)
//
#include <hip/hip_runtime.h>
#include <math.h>

#define CEPS 1e-9f

typedef _Float16 half8 __attribute__((ext_vector_type(8)));
typedef __fp16 fp16x2 __attribute__((ext_vector_type(2)));
typedef float floatx16 __attribute__((ext_vector_type(16)));

// x  : [4,56,56,8,32] fp32    W: [4,4,128,32] fp32    bias: [128] fp32
// out: [4,112,112,128] fp32 act
//
// votes[b'][pix][m=(pixl,i)][ca] = sum_{tap,ci} xf[...]*W[kh][kw][ca][ci]
// xf[b'][h][w][i][ci] = x[i&3][h][w][2b'+(i>>2)][ci]   (reference reshape scramble)
// Wave = M32 (4 pixels along v x 8 i), N=128 (4 tiles), K=128 (8 steps of 16).
// Block = 4 waves = 4x4 pixel tile, one parity (rh,rw), one b'. Single kernel:
// W converted fp32->f16 inline (cvt_pkrtz), L1/L2-resident.
// Routing: per-pixel LDS transpose (wave-local, no barrier) to lane=(c,i),
// a in-register -> squash/logit dots are in-lane; i-sums pure DPP.
//
// NOTE: launch_bounds min-waves MUST stay <=4: 64 acc regs share the unified
// VGPR file; bound 6 capped VGPRs at 80 and spilled 2.1 GB to scratch (R3).

template<int CTRL>
__device__ __forceinline__ float dpp_add(float v) {
    return v + __int_as_float(__builtin_amdgcn_update_dpp(
        0, __float_as_int(v), CTRL, 0xF, 0xF, false));
}

// sum over the 8-lane group (lane bits 0..2), result in all 8 lanes — pure VALU
__device__ __forceinline__ float sum_i8(float v) {
    v = dpp_add<0xB1>(v);    // quad_perm [1,0,3,2] == xor1
    v = dpp_add<0x4E>(v);    // quad_perm [2,3,0,1] == xor2
    v = dpp_add<0x141>(v);   // row_half_mirror: cross-quad (valid after quad sums)
    return v;
}

__device__ __forceinline__ float4 sel4(bool c, float4 a, float4 b) {
    return make_float4(c ? a.x : b.x, c ? a.y : b.y, c ? a.z : b.z, c ? a.w : b.w);
}

__global__ __launch_bounds__(256, 4) void caps_mfma(
    const float* __restrict__ x,
    const float* __restrict__ Wt,
    const float* __restrict__ bias,
    float* __restrict__ out)
{
    // x tile: [cell(5x5)][i(8)][ci padded 32->40] f16
    __shared__ _Float16 xt[25 * 8 * 40];       // 16000 B
    // per-wave vote-transpose scratch: [ca(128)][i(8)] fp32
    __shared__ float scx[4][1024];             // 16384 B

    const int tid = threadIdx.x;
    const int tile = blockIdx.x;            // 0..195 : 14x14 tiles of 4x4 pixels
    const int tu = tile / 14, tv = tile - tu * 14;
    const int u0 = tu * 4, v0 = tv * 4;
    const int rh = blockIdx.y >> 1;         // p & 1
    const int rw = blockIdx.y & 1;          // q & 1
    const int bp = blockIdx.z;              // b'

    // ---- stage x: fp32 -> f16 tile [ri(5)][rj(5)][i(8)][ci], zero-filled OOB ----
    #pragma unroll
    for (int it = 0; it < 4; ++it) {
        int idx = tid + (it << 8);
        if (idx < 800) {
            int cell = idx >> 5;            // 0..24
            int r = idx & 31;
            int i = r >> 2;
            int ci0 = (r & 3) << 3;
            int ri = cell / 5, rj = cell - ri * 5;
            int gi = u0 + rh - 1 + ri;
            int gj = v0 + rw - 1 + rj;
            float tmp[8] = {0.f, 0.f, 0.f, 0.f, 0.f, 0.f, 0.f, 0.f};
            if ((unsigned)gi < 56u && (unsigned)gj < 56u) {
                const float* src = x + (((i & 3) * 56 + gi) * 56 + gj) * 256
                                     + ((bp * 2 + (i >> 2)) << 5) + ci0;
                float4 a0 = *(const float4*)src;
                float4 a1 = *(const float4*)(src + 4);
                tmp[0] = a0.x; tmp[1] = a0.y; tmp[2] = a0.z; tmp[3] = a0.w;
                tmp[4] = a1.x; tmp[5] = a1.y; tmp[6] = a1.z; tmp[7] = a1.w;
            }
            half8 hv;
            #pragma unroll
            for (int j = 0; j < 8; ++j) hv[j] = (_Float16)tmp[j];
            *(half8*)(xt + (cell * 8 + i) * 40 + ci0) = hv;
        }
    }
    __syncthreads();

    const int l = tid & 63;
    const int w = tid >> 6;                 // wave = u-row within tile
    const int col = l & 31, h = l >> 5;
    const int invA = (l & 31) * 40 + (h << 3);

    floatx16 acc[4];
    #pragma unroll
    for (int t = 0; t < 4; ++t)
        #pragma unroll
        for (int j = 0; j < 16; ++j) acc[t][j] = 0.f;

    // ---- MFMA K-loop: 8 k-steps x 4 n-tiles; W converted inline from global fp32 ----
    #pragma unroll
    for (int s = 0; s < 8; ++s) {
        const int tkh = s >> 2;
        const int tkw = (s >> 1) & 1;
        const int row = w + 1 - tkh;
        const int aoff = (row * 5 + 1 - tkw) * 320 + ((s & 1) << 4) + invA;
        half8 af = *(const half8*)(xt + aoff);
        const int kh = (tkh << 1) + 1 - rh;
        const int kw = (tkw << 1) + 1 - rw;
        // B[k=s*16+h*8+j][n=t*32+col] = W[kh][kw][n][ci=16*(s&1)+8h+j]
        const float* wp0 = Wt + (((kh * 4 + kw) * 128 + col) << 5) + ((s & 1) << 4) + (h << 3);
        #pragma unroll
        for (int t = 0; t < 4; ++t) {
            const float* wp = wp0 + (t << 10);      // + t*32 rows * 32 ci
            float4 wa = *(const float4*)wp;
            float4 wb = *(const float4*)(wp + 4);
            union { half8 h8; fp16x2 h2[4]; } u;
            u.h2[0] = __builtin_amdgcn_cvt_pkrtz(wa.x, wa.y);
            u.h2[1] = __builtin_amdgcn_cvt_pkrtz(wa.z, wa.w);
            u.h2[2] = __builtin_amdgcn_cvt_pkrtz(wb.x, wb.y);
            u.h2[3] = __builtin_amdgcn_cvt_pkrtz(wb.z, wb.w);
            acc[t] = __builtin_amdgcn_mfma_f32_32x32x16_f16(af, u.h8, acc[t], 0, 0, 0);
        }
    }

    // ---- routing: lane = (c = l>>3, i = l&7), a(16) in-register ----
    float* scb = &scx[w][0];                // wave-local, no barrier needed
    const int cI = l >> 3;
    const int iI = l & 7;

    float4 bq[4];                           // bias[c*16 + a]
    #pragma unroll
    for (int t = 0; t < 4; ++t) bq[t] = *(const float4*)(bias + cI * 16 + t * 4);

    #pragma unroll
    for (int pixl = 0; pixl < 4; ++pixl) {
        // transpose this pixel's votes: C-layout -> [ca][i]; b128 writes, conflict-free
        #pragma unroll
        for (int t = 0; t < 4; ++t) {
            float4 v4 = make_float4(acc[t][pixl * 4 + 0], acc[t][pixl * 4 + 1],
                                    acc[t][pixl * 4 + 2], acc[t][pixl * 4 + 3]);
            *(float4*)(scb + ((t * 32 + col) << 3) + (h << 2)) = v4;
        }
        float va[16];
        #pragma unroll
        for (int a = 0; a < 16; ++a) va[a] = scb[((cI * 16 + a) << 3) + iI];

        float pre[16], lg = 0.f;

        // ---- round 0: route = 1/8 ----
        #pragma unroll
        for (int a = 0; a < 16; ++a) {
            float s = sum_i8(va[a]);
            pre[a] = fmaf(0.125f, s, (&bq[a >> 2].x)[a & 3]);
        }
        {
            float nq = pre[0] * pre[0];
            #pragma unroll
            for (int a = 1; a < 16; ++a) nq = fmaf(pre[a], pre[a], nq);
            float sc = nq * __builtin_amdgcn_rcpf(1.f + nq)
                          * __builtin_amdgcn_rsqf(nq + CEPS);
            #pragma unroll
            for (int a = 0; a < 16; ++a) pre[a] *= sc;   // pre = act now
            float d = va[0] * pre[0];
            #pragma unroll
            for (int a = 1; a < 16; ++a) d = fmaf(va[a], pre[a], d);
            lg = d;                                       // per-(i,c), no shuffle
        }

        // ---- rounds 1,2 ----
        #pragma unroll
        for (int r = 1; r < 3; ++r) {
            // softmax over c (lane bits 3..5); logits bounded, no max-sub
            float e = __expf(lg);
            float ss = dpp_add<0x128>(e);                 // ror8 == xor8
            ss += __shfl_xor(ss, 16);
            ss += __shfl_xor(ss, 32);
            float route = e * __builtin_amdgcn_rcpf(ss);
            #pragma unroll
            for (int a = 0; a < 16; ++a) {
                float m = sum_i8(route * va[a]);
                pre[a] = m + (&bq[a >> 2].x)[a & 3];
            }
            float nq = pre[0] * pre[0];
            #pragma unroll
            for (int a = 1; a < 16; ++a) nq = fmaf(pre[a], pre[a], nq);
            float sc = nq * __builtin_amdgcn_rcpf(1.f + nq)
                          * __builtin_amdgcn_rsqf(nq + CEPS);
            #pragma unroll
            for (int a = 0; a < 16; ++a) pre[a] *= sc;    // act
            if (r < 2) {
                float d = va[0] * pre[0];
                #pragma unroll
                for (int a = 1; a < 16; ++a) d = fmaf(va[a], pre[a], d);
                lg += d;
            }
        }

        // ---- store: lanes i<4 each write one float4 quad -> fully coalesced ----
        float4 q0 = make_float4(pre[0],  pre[1],  pre[2],  pre[3]);
        float4 q1 = make_float4(pre[4],  pre[5],  pre[6],  pre[7]);
        float4 q2 = make_float4(pre[8],  pre[9],  pre[10], pre[11]);
        float4 q3 = make_float4(pre[12], pre[13], pre[14], pre[15]);
        float4 t0 = sel4((iI & 1) != 0, q1, q0);
        float4 t1 = sel4((iI & 1) != 0, q3, q2);
        float4 o4 = sel4((iI & 2) != 0, t1, t0);
        if (iI < 4) {
            const int p = ((u0 + w) << 1) + rh;
            const int q = ((v0 + pixl) << 1) + rw;
            *(float4*)(out + (((bp * 112 + p) * 112 + q) << 7) + cI * 16 + iI * 4) = o4;
        }
    }
}

extern "C" void kernel_launch(void* const* d_in, const int* in_sizes, int n_in,
                              void* d_out, int out_size, void* d_ws, size_t ws_size,
                              hipStream_t stream) {
    const float* x  = (const float*)d_in[0];
    const float* Wt = (const float*)d_in[1];
    const float* b  = (const float*)d_in[2];
    float* out = (float*)d_out;
    dim3 grid(196, 4, 4);    // 14x14 4x4-pixel tiles, 4 parity classes, 4 b'
    caps_mfma<<<grid, 256, 0, stream>>>(x, Wt, b, out);
}

// Round 7
// 171.575 us; speedup vs baseline: 1.6123x; 1.6123x over previous
//
#include <hip/hip_runtime.h>
#include <math.h>

#define CEPS 1e-9f

typedef _Float16 half8 __attribute__((ext_vector_type(8)));
typedef __fp16 fp16x2 __attribute__((ext_vector_type(2)));
typedef float floatx16 __attribute__((ext_vector_type(16)));

// x  : [4,56,56,8,32] fp32    W: [4,4,128,32] fp32    bias: [128] fp32
// out: [4,112,112,128] fp32 act
//
// votes[b'][pix][m=(pixl,i)][ca] = sum_{tap,ci} xf[...]*W[kh][kw][ca][ci]
// xf[b'][h][w][i][ci] = x[i&3][h][w][2b'+(i>>2)][ci]   (reference reshape scramble)
// Wave = M32 (4 pixels along v x 8 i), N=128 (4 tiles), K=128 (8 steps of 16).
// Block = 4 waves = 4x4 pixel tile, one parity (rh,rw), one b'. Single kernel:
// W converted fp32->f16 inline (cvt_pkrtz), L1/L2-resident.
// Routing: per-pixel LDS transpose (wave-local, no barrier) to lane=(c,i),
// a in-register -> squash/logit dots in-lane; i-sums pure DPP.
//
// REGISTER NOTE: peak live = acc(64) + va(16) + pre(16) + bq(16) + misc ~= 150.
//   bounds (256,4) caps VGPR at 128 -> 400 MB scratch spill (R6: 224 us).
//   bounds (256,6) caps at 85      -> 2.1 GB spill (R3: 572 us).
//   (256,3) caps ~170: fits. Occupancy 3 blocks/CU is the price; spill is worse.
// scx row stride 9 floats: stride-8 made all 8 cI rows alias to the same banks
// (8-way conflict on va reads, 6.7M conflict cycles in R6).

template<int CTRL>
__device__ __forceinline__ float dpp_add(float v) {
    return v + __int_as_float(__builtin_amdgcn_update_dpp(
        0, __float_as_int(v), CTRL, 0xF, 0xF, false));
}

// sum over the 8-lane group (lane bits 0..2), result in all 8 lanes — pure VALU
__device__ __forceinline__ float sum_i8(float v) {
    v = dpp_add<0xB1>(v);    // quad_perm [1,0,3,2] == xor1
    v = dpp_add<0x4E>(v);    // quad_perm [2,3,0,1] == xor2
    v = dpp_add<0x141>(v);   // row_half_mirror: cross-quad (valid after quad sums)
    return v;
}

__device__ __forceinline__ float4 sel4(bool c, float4 a, float4 b) {
    return make_float4(c ? a.x : b.x, c ? a.y : b.y, c ? a.z : b.z, c ? a.w : b.w);
}

__global__ __launch_bounds__(256, 3) void caps_mfma(
    const float* __restrict__ x,
    const float* __restrict__ Wt,
    const float* __restrict__ bias,
    float* __restrict__ out)
{
    // x tile: [cell(5x5)][i(8)][ci padded 32->40] f16
    __shared__ _Float16 xt[25 * 8 * 40];       // 16000 B
    // per-wave vote-transpose scratch: [ca(128)][i(8) padded ->9] fp32
    __shared__ float scx[4][1152];             // 18432 B

    const int tid = threadIdx.x;
    const int tile = blockIdx.x;            // 0..195 : 14x14 tiles of 4x4 pixels
    const int tu = tile / 14, tv = tile - tu * 14;
    const int u0 = tu * 4, v0 = tv * 4;
    const int rh = blockIdx.y >> 1;         // p & 1
    const int rw = blockIdx.y & 1;          // q & 1
    const int bp = blockIdx.z;              // b'

    // ---- stage x: fp32 -> f16 tile [ri(5)][rj(5)][i(8)][ci], zero-filled OOB ----
    #pragma unroll
    for (int it = 0; it < 4; ++it) {
        int idx = tid + (it << 8);
        if (idx < 800) {
            int cell = idx >> 5;            // 0..24
            int r = idx & 31;
            int i = r >> 2;
            int ci0 = (r & 3) << 3;
            int ri = cell / 5, rj = cell - ri * 5;
            int gi = u0 + rh - 1 + ri;
            int gj = v0 + rw - 1 + rj;
            float tmp[8] = {0.f, 0.f, 0.f, 0.f, 0.f, 0.f, 0.f, 0.f};
            if ((unsigned)gi < 56u && (unsigned)gj < 56u) {
                const float* src = x + (((i & 3) * 56 + gi) * 56 + gj) * 256
                                     + ((bp * 2 + (i >> 2)) << 5) + ci0;
                float4 a0 = *(const float4*)src;
                float4 a1 = *(const float4*)(src + 4);
                tmp[0] = a0.x; tmp[1] = a0.y; tmp[2] = a0.z; tmp[3] = a0.w;
                tmp[4] = a1.x; tmp[5] = a1.y; tmp[6] = a1.z; tmp[7] = a1.w;
            }
            half8 hv;
            #pragma unroll
            for (int j = 0; j < 8; ++j) hv[j] = (_Float16)tmp[j];
            *(half8*)(xt + (cell * 8 + i) * 40 + ci0) = hv;
        }
    }
    __syncthreads();

    const int l = tid & 63;
    const int w = tid >> 6;                 // wave = u-row within tile
    const int col = l & 31, h = l >> 5;
    const int invA = (l & 31) * 40 + (h << 3);

    floatx16 acc[4];
    #pragma unroll
    for (int t = 0; t < 4; ++t)
        #pragma unroll
        for (int j = 0; j < 16; ++j) acc[t][j] = 0.f;

    // ---- MFMA K-loop: 8 k-steps x 4 n-tiles; W converted inline from global fp32 ----
    #pragma unroll
    for (int s = 0; s < 8; ++s) {
        const int tkh = s >> 2;
        const int tkw = (s >> 1) & 1;
        const int row = w + 1 - tkh;
        const int aoff = (row * 5 + 1 - tkw) * 320 + ((s & 1) << 4) + invA;
        half8 af = *(const half8*)(xt + aoff);
        const int kh = (tkh << 1) + 1 - rh;
        const int kw = (tkw << 1) + 1 - rw;
        // B[k=s*16+h*8+j][n=t*32+col] = W[kh][kw][n][ci=16*(s&1)+8h+j]
        const float* wp0 = Wt + (((kh * 4 + kw) * 128 + col) << 5) + ((s & 1) << 4) + (h << 3);
        #pragma unroll
        for (int t = 0; t < 4; ++t) {
            const float* wp = wp0 + (t << 10);      // + t*32 rows * 32 ci
            float4 wa = *(const float4*)wp;
            float4 wb = *(const float4*)(wp + 4);
            union { half8 h8; fp16x2 h2[4]; } u;
            u.h2[0] = __builtin_amdgcn_cvt_pkrtz(wa.x, wa.y);
            u.h2[1] = __builtin_amdgcn_cvt_pkrtz(wa.z, wa.w);
            u.h2[2] = __builtin_amdgcn_cvt_pkrtz(wb.x, wb.y);
            u.h2[3] = __builtin_amdgcn_cvt_pkrtz(wb.z, wb.w);
            acc[t] = __builtin_amdgcn_mfma_f32_32x32x16_f16(af, u.h8, acc[t], 0, 0, 0);
        }
    }

    // ---- routing: lane = (c = l>>3, i = l&7), a(16) in-register ----
    float* scb = &scx[w][0];                // wave-local, no barrier needed
    const int cI = l >> 3;
    const int iI = l & 7;

    float4 bq[4];                           // bias[c*16 + a]
    #pragma unroll
    for (int t = 0; t < 4; ++t) bq[t] = *(const float4*)(bias + cI * 16 + t * 4);

    #pragma unroll
    for (int pixl = 0; pixl < 4; ++pixl) {
        // transpose this pixel's votes: C-layout -> [ca][i] (row stride 9)
        // write bank = (9*col + 4h + il) % 32 : 64 lanes / 64 distinct -> 2-way, free
        #pragma unroll
        for (int t = 0; t < 4; ++t)
            #pragma unroll
            for (int il = 0; il < 4; ++il)
                scb[(t * 32 + col) * 9 + (h << 2) + il] = acc[t][pixl * 4 + il];
        float va[16];
        #pragma unroll
        for (int a = 0; a < 16; ++a) va[a] = scb[(cI * 16 + a) * 9 + iI];

        float pre[16], lg = 0.f;

        // ---- round 0: route = 1/8 ----
        #pragma unroll
        for (int a = 0; a < 16; ++a) {
            float s = sum_i8(va[a]);
            pre[a] = fmaf(0.125f, s, (&bq[a >> 2].x)[a & 3]);
        }
        {
            float nq = pre[0] * pre[0];
            #pragma unroll
            for (int a = 1; a < 16; ++a) nq = fmaf(pre[a], pre[a], nq);
            float sc = nq * __builtin_amdgcn_rcpf(1.f + nq)
                          * __builtin_amdgcn_rsqf(nq + CEPS);
            #pragma unroll
            for (int a = 0; a < 16; ++a) pre[a] *= sc;   // pre = act now
            float d = va[0] * pre[0];
            #pragma unroll
            for (int a = 1; a < 16; ++a) d = fmaf(va[a], pre[a], d);
            lg = d;                                       // per-(i,c), no shuffle
        }

        // ---- rounds 1,2 ----
        #pragma unroll
        for (int r = 1; r < 3; ++r) {
            // softmax over c (lane bits 3..5); logits bounded, no max-sub
            float e = __expf(lg);
            float ss = dpp_add<0x128>(e);                 // ror8 == xor8
            ss += __shfl_xor(ss, 16);
            ss += __shfl_xor(ss, 32);
            float route = e * __builtin_amdgcn_rcpf(ss);
            #pragma unroll
            for (int a = 0; a < 16; ++a) {
                float m = sum_i8(route * va[a]);
                pre[a] = m + (&bq[a >> 2].x)[a & 3];
            }
            float nq = pre[0] * pre[0];
            #pragma unroll
            for (int a = 1; a < 16; ++a) nq = fmaf(pre[a], pre[a], nq);
            float sc = nq * __builtin_amdgcn_rcpf(1.f + nq)
                          * __builtin_amdgcn_rsqf(nq + CEPS);
            #pragma unroll
            for (int a = 0; a < 16; ++a) pre[a] *= sc;    // act
            if (r < 2) {
                float d = va[0] * pre[0];
                #pragma unroll
                for (int a = 1; a < 16; ++a) d = fmaf(va[a], pre[a], d);
                lg += d;
            }
        }

        // ---- store: lanes i<4 each write one float4 quad -> fully coalesced ----
        float4 q0 = make_float4(pre[0],  pre[1],  pre[2],  pre[3]);
        float4 q1 = make_float4(pre[4],  pre[5],  pre[6],  pre[7]);
        float4 q2 = make_float4(pre[8],  pre[9],  pre[10], pre[11]);
        float4 q3 = make_float4(pre[12], pre[13], pre[14], pre[15]);
        float4 t0 = sel4((iI & 1) != 0, q1, q0);
        float4 t1 = sel4((iI & 1) != 0, q3, q2);
        float4 o4 = sel4((iI & 2) != 0, t1, t0);
        if (iI < 4) {
            const int p = ((u0 + w) << 1) + rh;
            const int q = ((v0 + pixl) << 1) + rw;
            *(float4*)(out + (((bp * 112 + p) * 112 + q) << 7) + cI * 16 + iI * 4) = o4;
        }
    }
}

extern "C" void kernel_launch(void* const* d_in, const int* in_sizes, int n_in,
                              void* d_out, int out_size, void* d_ws, size_t ws_size,
                              hipStream_t stream) {
    const float* x  = (const float*)d_in[0];
    const float* Wt = (const float*)d_in[1];
    const float* b  = (const float*)d_in[2];
    float* out = (float*)d_out;
    dim3 grid(196, 4, 4);    // 14x14 4x4-pixel tiles, 4 parity classes, 4 b'
    caps_mfma<<<grid, 256, 0, stream>>>(x, Wt, b, out);
}

// Round 8
// 122.320 us; speedup vs baseline: 2.2616x; 1.4027x over previous
//
#include <hip/hip_runtime.h>
#include <math.h>

#define CEPS 1e-9f

typedef _Float16 half8 __attribute__((ext_vector_type(8)));
typedef float floatx16 __attribute__((ext_vector_type(16)));

// x  : [4,56,56,8,32] fp32    W: [4,4,128,32] fp32    bias: [128] fp32
// out: [4,112,112,128] fp32 act
//
// votes[b'][pix][m=(pixl,i)][ca] = sum_{tap,ci} xf[...]*W[kh][kw][ca][ci]
// xf[b'][h][w][i][ci] = x[i&3][h][w][2b'+(i>>2)][ci]   (reference reshape scramble)
// Wave = M32 (4 pixels along v x 8 i), N=128 (4 tiles), K=128 (8 steps of 16).
// Block = 4 waves = 4x4 pixel tile, one parity (rh,rw), one b'.
// W staged by prep_w as f16 B-fragments in d_ws (16 KB/parity -> L1-resident;
// R7 measured: inline fp32 W fetch+convert from 64 KB costs ~45 us of L2-latency
// stall vs the table: 116 us vs 83 us-class K-loop).
// Routing: per-pixel LDS transpose (wave-local, no barrier) to lane=(c,i),
// a in-register -> squash/logit dots in-lane; i-sums pure DPP.
//
// REGISTER NOTE: peak live ~= acc(64) + va(16) + pre(16) + bq(16) + misc.
//   bounds (256,4) caps VGPR at 128 -> 400 MB scratch spill (R6: 224 us).
//   bounds (256,6) caps at 85      -> 2.1 GB spill (R3: 572 us).
//   (256,3) caps ~170: fits, no spill (R7: FETCH/WRITE 24/25 MB).
// scx row stride 9 floats: stride-8 aliased all 8 cI rows to the same banks
// (8-way conflict, 6.7M cyc in R6; 1.9M at stride 9 in R7).

template<int CTRL>
__device__ __forceinline__ float dpp_add(float v) {
    return v + __int_as_float(__builtin_amdgcn_update_dpp(
        0, __float_as_int(v), CTRL, 0xF, 0xF, false));
}

// sum over the 8-lane group (lane bits 0..2), result in all 8 lanes — pure VALU
__device__ __forceinline__ float sum_i8(float v) {
    v = dpp_add<0xB1>(v);    // quad_perm [1,0,3,2] == xor1
    v = dpp_add<0x4E>(v);    // quad_perm [2,3,0,1] == xor2
    v = dpp_add<0x141>(v);   // row_half_mirror: cross-quad (valid after quad sums)
    return v;
}

__device__ __forceinline__ float4 sel4(bool c, float4 a, float4 b) {
    return make_float4(c ? a.x : b.x, c ? a.y : b.y, c ? a.z : b.z, c ? a.w : b.w);
}

// B[k][n] fragment table: idx = ((parity*8 + s)*4 + t)*64 + l -> 8 f16
__global__ __launch_bounds__(256) void prep_w(const float* __restrict__ Wt,
                                              _Float16* __restrict__ wb) {
    int idx = blockIdx.x * 256 + threadIdx.x;    // [0, 8192)
    int parity = idx >> 11;
    int s = (idx >> 8) & 7;
    int t = (idx >> 6) & 3;
    int l = idx & 63;
    int rh = parity >> 1, rw = parity & 1;
    int n = t * 32 + (l & 31);
    int h = l >> 5;
    int ci0 = ((s & 1) << 4) + (h << 3);
    int kh = ((s >> 2) << 1) + 1 - rh;
    int kw = (((s >> 1) & 1) << 1) + 1 - rw;
    const float* src = Wt + (((kh * 4 + kw) * 128 + n) << 5) + ci0;
    float4 w0 = *(const float4*)src;
    float4 w1 = *(const float4*)(src + 4);
    half8 hv;
    hv[0] = (_Float16)w0.x; hv[1] = (_Float16)w0.y;
    hv[2] = (_Float16)w0.z; hv[3] = (_Float16)w0.w;
    hv[4] = (_Float16)w1.x; hv[5] = (_Float16)w1.y;
    hv[6] = (_Float16)w1.z; hv[7] = (_Float16)w1.w;
    *(half8*)(wb + ((long)idx << 3)) = hv;
}

__global__ __launch_bounds__(256, 3) void caps_mfma(
    const float* __restrict__ x,
    const _Float16* __restrict__ wb,
    const float* __restrict__ bias,
    float* __restrict__ out)
{
    // x tile: [cell(5x5)][i(8)][ci padded 32->40] f16
    __shared__ _Float16 xt[25 * 8 * 40];       // 16000 B
    // per-wave vote-transpose scratch: [ca(128)][i(8) padded ->9] fp32
    __shared__ float scx[4][1152];             // 18432 B

    const int tid = threadIdx.x;
    const int tile = blockIdx.x;            // 0..195 : 14x14 tiles of 4x4 pixels
    const int tu = tile / 14, tv = tile - tu * 14;
    const int u0 = tu * 4, v0 = tv * 4;
    const int rh = blockIdx.y >> 1;         // p & 1
    const int rw = blockIdx.y & 1;          // q & 1
    const int bp = blockIdx.z;              // b'
    const _Float16* wsrc = wb + ((long)blockIdx.y << 14);   // parity slice, 16 KB

    // ---- stage x: fp32 -> f16 tile [ri(5)][rj(5)][i(8)][ci], zero-filled OOB ----
    #pragma unroll
    for (int it = 0; it < 4; ++it) {
        int idx = tid + (it << 8);
        if (idx < 800) {
            int cell = idx >> 5;            // 0..24
            int r = idx & 31;
            int i = r >> 2;
            int ci0 = (r & 3) << 3;
            int ri = cell / 5, rj = cell - ri * 5;
            int gi = u0 + rh - 1 + ri;
            int gj = v0 + rw - 1 + rj;
            float tmp[8] = {0.f, 0.f, 0.f, 0.f, 0.f, 0.f, 0.f, 0.f};
            if ((unsigned)gi < 56u && (unsigned)gj < 56u) {
                const float* src = x + (((i & 3) * 56 + gi) * 56 + gj) * 256
                                     + ((bp * 2 + (i >> 2)) << 5) + ci0;
                float4 a0 = *(const float4*)src;
                float4 a1 = *(const float4*)(src + 4);
                tmp[0] = a0.x; tmp[1] = a0.y; tmp[2] = a0.z; tmp[3] = a0.w;
                tmp[4] = a1.x; tmp[5] = a1.y; tmp[6] = a1.z; tmp[7] = a1.w;
            }
            half8 hv;
            #pragma unroll
            for (int j = 0; j < 8; ++j) hv[j] = (_Float16)tmp[j];
            *(half8*)(xt + (cell * 8 + i) * 40 + ci0) = hv;
        }
    }
    __syncthreads();

    const int l = tid & 63;
    const int w = tid >> 6;                 // wave = u-row within tile
    const int col = l & 31, h = l >> 5;
    const int invA = (l & 31) * 40 + (h << 3);

    floatx16 acc[4];
    #pragma unroll
    for (int t = 0; t < 4; ++t)
        #pragma unroll
        for (int j = 0; j < 16; ++j) acc[t][j] = 0.f;

    // ---- MFMA K-loop: 8 k-steps x 4 n-tiles; B-frags from L1-resident table ----
    #pragma unroll
    for (int s = 0; s < 8; ++s) {
        const int tkh = s >> 2;
        const int tkw = (s >> 1) & 1;
        const int row = w + 1 - tkh;
        const int aoff = (row * 5 + 1 - tkw) * 320 + ((s & 1) << 4) + invA;
        half8 af = *(const half8*)(xt + aoff);
        #pragma unroll
        for (int t = 0; t < 4; ++t) {
            half8 bf = *(const half8*)(wsrc + (((s * 4 + t) * 64 + l) << 3));
            acc[t] = __builtin_amdgcn_mfma_f32_32x32x16_f16(af, bf, acc[t], 0, 0, 0);
        }
    }

    // ---- routing: lane = (c = l>>3, i = l&7), a(16) in-register ----
    float* scb = &scx[w][0];                // wave-local, no barrier needed
    const int cI = l >> 3;
    const int iI = l & 7;

    float4 bq[4];                           // bias[c*16 + a]
    #pragma unroll
    for (int t = 0; t < 4; ++t) bq[t] = *(const float4*)(bias + cI * 16 + t * 4);

    #pragma unroll
    for (int pixl = 0; pixl < 4; ++pixl) {
        // transpose this pixel's votes: C-layout -> [ca][i] (row stride 9)
        #pragma unroll
        for (int t = 0; t < 4; ++t)
            #pragma unroll
            for (int il = 0; il < 4; ++il)
                scb[(t * 32 + col) * 9 + (h << 2) + il] = acc[t][pixl * 4 + il];
        float va[16];
        #pragma unroll
        for (int a = 0; a < 16; ++a) va[a] = scb[(cI * 16 + a) * 9 + iI];

        float pre[16], lg = 0.f;

        // ---- round 0: route = 1/8 ----
        #pragma unroll
        for (int a = 0; a < 16; ++a) {
            float s = sum_i8(va[a]);
            pre[a] = fmaf(0.125f, s, (&bq[a >> 2].x)[a & 3]);
        }
        {
            float nq = pre[0] * pre[0];
            #pragma unroll
            for (int a = 1; a < 16; ++a) nq = fmaf(pre[a], pre[a], nq);
            float sc = nq * __builtin_amdgcn_rcpf(1.f + nq)
                          * __builtin_amdgcn_rsqf(nq + CEPS);
            #pragma unroll
            for (int a = 0; a < 16; ++a) pre[a] *= sc;   // pre = act now
            float d = va[0] * pre[0];
            #pragma unroll
            for (int a = 1; a < 16; ++a) d = fmaf(va[a], pre[a], d);
            lg = d;                                       // per-(i,c), no shuffle
        }

        // ---- rounds 1,2 ----
        #pragma unroll
        for (int r = 1; r < 3; ++r) {
            // softmax over c (lane bits 3..5); logits bounded, no max-sub
            float e = __expf(lg);
            float ss = dpp_add<0x128>(e);                 // ror8 == xor8
            ss += __shfl_xor(ss, 16);
            ss += __shfl_xor(ss, 32);
            float route = e * __builtin_amdgcn_rcpf(ss);
            #pragma unroll
            for (int a = 0; a < 16; ++a) {
                float m = sum_i8(route * va[a]);
                pre[a] = m + (&bq[a >> 2].x)[a & 3];
            }
            float nq = pre[0] * pre[0];
            #pragma unroll
            for (int a = 1; a < 16; ++a) nq = fmaf(pre[a], pre[a], nq);
            float sc = nq * __builtin_amdgcn_rcpf(1.f + nq)
                          * __builtin_amdgcn_rsqf(nq + CEPS);
            #pragma unroll
            for (int a = 0; a < 16; ++a) pre[a] *= sc;    // act
            if (r < 2) {
                float d = va[0] * pre[0];
                #pragma unroll
                for (int a = 1; a < 16; ++a) d = fmaf(va[a], pre[a], d);
                lg += d;
            }
        }

        // ---- store: lanes i<4 each write one float4 quad -> fully coalesced ----
        float4 q0 = make_float4(pre[0],  pre[1],  pre[2],  pre[3]);
        float4 q1 = make_float4(pre[4],  pre[5],  pre[6],  pre[7]);
        float4 q2 = make_float4(pre[8],  pre[9],  pre[10], pre[11]);
        float4 q3 = make_float4(pre[12], pre[13], pre[14], pre[15]);
        float4 t0 = sel4((iI & 1) != 0, q1, q0);
        float4 t1 = sel4((iI & 1) != 0, q3, q2);
        float4 o4 = sel4((iI & 2) != 0, t1, t0);
        if (iI < 4) {
            const int p = ((u0 + w) << 1) + rh;
            const int q = ((v0 + pixl) << 1) + rw;
            *(float4*)(out + (((bp * 112 + p) * 112 + q) << 7) + cI * 16 + iI * 4) = o4;
        }
    }
}

extern "C" void kernel_launch(void* const* d_in, const int* in_sizes, int n_in,
                              void* d_out, int out_size, void* d_ws, size_t ws_size,
                              hipStream_t stream) {
    const float* x  = (const float*)d_in[0];
    const float* Wt = (const float*)d_in[1];
    const float* b  = (const float*)d_in[2];
    float* out = (float*)d_out;
    _Float16* wb = (_Float16*)d_ws;          // 4 parities x 16384 f16 = 64 KB

    prep_w<<<32, 256, 0, stream>>>(Wt, wb);
    dim3 grid(196, 4, 4);    // 14x14 4x4-pixel tiles, 4 parity classes, 4 b'
    caps_mfma<<<grid, 256, 0, stream>>>(x, wb, b, out);
}